// Round 2
// baseline (109.850 us; speedup 1.0000x reference)
//
#include <hip/hip_runtime.h>

// Problem constants (match reference.py)
#define NB 65536   // trajectories
#define NT 512     // time points (NT-1 steps)

typedef float f32x2 __attribute__((ext_vector_type(2)));

__global__ __launch_bounds__(256) void rk4_biosystem_kernel(
    const float* __restrict__ y0,
    const float* __restrict__ t_eval,
    const float* __restrict__ D_seq,
    const float* __restrict__ K_m_p,
    const float* __restrict__ s_e_p,
    const float* __restrict__ mu_max_p,
    float* __restrict__ out)
{
    __shared__ float s_dt[NT - 1];
    __shared__ float s_D[NT - 1];

    const int tid = threadIdx.x;
    // Stage per-step uniforms into LDS (dt exactly as reference: t[i+1]-t[i])
    for (int i = tid; i < NT - 1; i += 256) {
        s_dt[i] = t_eval[i + 1] - t_eval[i];
        s_D[i]  = D_seq[i];
    }
    __syncthreads();

    const float K_m    = K_m_p[0];
    const float s_e    = s_e_p[0];
    const float mu_max = mu_max_p[0];

    const int traj = blockIdx.x * 256 + tid;

    float b = y0[traj * 2 + 0];
    float s = y0[traj * 2 + 1];

    f32x2* __restrict__ out2 = (f32x2*)out;  // out[t][traj][2] as vec2

    // out[0] = y0
    {
        f32x2 v; v.x = b; v.y = s;
        __builtin_nontemporal_store(v, &out2[traj]);
    }

    #pragma unroll 1
    for (int t = 0; t < NT - 1; ++t) {
        const float dt = s_dt[t];
        const float D  = s_D[t];

        // rhs(b,s): rho = mu_max*s/(K_m+s); db = -D*b + rho*b; ds = D*(s_e-s) - rho*b
        #define RHS(bb, ss, db, ds)                      \
            {                                            \
                float rho = mu_max * (ss) / (K_m + (ss));\
                float rb  = rho * (bb);                  \
                db = rb - D * (bb);                      \
                ds = D * (s_e - (ss)) - rb;              \
            }

        float k1b, k1s, k2b, k2s, k3b, k3s, k4b, k4s;
        RHS(b, s, k1b, k1s);
        const float h2 = dt * 0.5f;
        RHS(b + h2 * k1b, s + h2 * k1s, k2b, k2s);
        RHS(b + h2 * k2b, s + h2 * k2s, k3b, k3s);
        RHS(b + dt * k3b, s + dt * k3s, k4b, k4s);

        const float h6 = dt * (1.0f / 6.0f);
        b = b + h6 * (k1b + 2.0f * k2b + 2.0f * k3b + k4b);
        s = s + h6 * (k1s + 2.0f * k2s + 2.0f * k3s + k4s);

        f32x2 v; v.x = b; v.y = s;
        __builtin_nontemporal_store(v, &out2[(t + 1) * NB + traj]);
        #undef RHS
    }
}

extern "C" void kernel_launch(void* const* d_in, const int* in_sizes, int n_in,
                              void* d_out, int out_size, void* d_ws, size_t ws_size,
                              hipStream_t stream) {
    const float* y0     = (const float*)d_in[0];
    const float* t_eval = (const float*)d_in[1];
    const float* D_seq  = (const float*)d_in[2];
    const float* K_m    = (const float*)d_in[3];
    const float* s_e    = (const float*)d_in[4];
    const float* mu_max = (const float*)d_in[5];
    float* out = (float*)d_out;

    dim3 grid(NB / 256);
    dim3 block(256);
    rk4_biosystem_kernel<<<grid, block, 0, stream>>>(y0, t_eval, D_seq, K_m, s_e, mu_max, out);
}

// Round 3
// 78.903 us; speedup vs baseline: 1.3922x; 1.3922x over previous
//
#include <hip/hip_runtime.h>

// Problem constants (match reference.py)
#define NB 65536   // trajectories
#define NT 512     // time points (NT-1 steps)

typedef float f32x2 __attribute__((ext_vector_type(2)));

__global__ __launch_bounds__(256) void rk4_biosystem_kernel(
    const float* __restrict__ y0,
    const float* __restrict__ t_eval,
    const float* __restrict__ D_seq,
    const float* __restrict__ K_m_p,
    const float* __restrict__ s_e_p,
    const float* __restrict__ mu_max_p,
    float* __restrict__ out)
{
    __shared__ float s_dt[NT - 1];
    __shared__ float s_D[NT - 1];

    const int tid = threadIdx.x;
    // Stage per-step uniforms into LDS (dt exactly as reference: t[i+1]-t[i])
    for (int i = tid; i < NT - 1; i += 256) {
        s_dt[i] = t_eval[i + 1] - t_eval[i];
        s_D[i]  = D_seq[i];
    }
    __syncthreads();

    const float K_m    = K_m_p[0];
    const float s_e    = s_e_p[0];
    const float mu_max = mu_max_p[0];

    const int traj = blockIdx.x * 256 + tid;

    float b = y0[traj * 2 + 0];
    float s = y0[traj * 2 + 1];

    f32x2* __restrict__ out2 = (f32x2*)out;  // out[t][traj][2] as vec2

    // out[0] = y0
    {
        f32x2 v; v.x = b; v.y = s;
        __builtin_nontemporal_store(v, &out2[traj]);
    }

    // Software-pipelined LDS reads: dt/D for step t are loaded during step t-1,
    // hiding the ~120cyc ds_read latency under the RK4 compute chain.
    float dt_c = s_dt[0];
    float D_c  = s_D[0];

    // rhs(b,s): rho = mu_max*s/(K_m+s); db = -D*b + rho*b; ds = D*(s_e-s) - rho*b
    // Fast reciprocal (v_rcp_f32, ~1ulp) instead of the IEEE divide sequence.
    #define RHS(bb, ss, db, ds)                                     \
        {                                                           \
            float inv = __builtin_amdgcn_rcpf(K_m + (ss));          \
            float rb  = (mu_max * (ss)) * (inv * (bb));             \
            db = __builtin_fmaf(-D, (bb), rb);                      \
            ds = __builtin_fmaf(D, s_e - (ss), -rb);                \
        }

    #pragma unroll 2
    for (int t = 0; t < NT - 1; ++t) {
        const float dt = dt_c;
        const float D  = D_c;
        // prefetch next step's uniforms (clamped index on last iteration)
        const int tn = (t < NT - 2) ? (t + 1) : t;
        dt_c = s_dt[tn];
        D_c  = s_D[tn];

        float k1b, k1s, k2b, k2s, k3b, k3s, k4b, k4s;
        RHS(b, s, k1b, k1s);
        const float h2 = dt * 0.5f;
        RHS(__builtin_fmaf(h2, k1b, b), __builtin_fmaf(h2, k1s, s), k2b, k2s);
        RHS(__builtin_fmaf(h2, k2b, b), __builtin_fmaf(h2, k2s, s), k3b, k3s);
        RHS(__builtin_fmaf(dt, k3b, b), __builtin_fmaf(dt, k3s, s), k4b, k4s);

        const float h6 = dt * (1.0f / 6.0f);
        const float sb = k1b + 2.0f * k2b + 2.0f * k3b + k4b;
        const float ss_ = k1s + 2.0f * k2s + 2.0f * k3s + k4s;
        b = __builtin_fmaf(h6, sb, b);
        s = __builtin_fmaf(h6, ss_, s);

        f32x2 v; v.x = b; v.y = s;
        __builtin_nontemporal_store(v, &out2[(t + 1) * NB + traj]);
    }
    #undef RHS
}

extern "C" void kernel_launch(void* const* d_in, const int* in_sizes, int n_in,
                              void* d_out, int out_size, void* d_ws, size_t ws_size,
                              hipStream_t stream) {
    const float* y0     = (const float*)d_in[0];
    const float* t_eval = (const float*)d_in[1];
    const float* D_seq  = (const float*)d_in[2];
    const float* K_m    = (const float*)d_in[3];
    const float* s_e    = (const float*)d_in[4];
    const float* mu_max = (const float*)d_in[5];
    float* out = (float*)d_out;

    dim3 grid(NB / 256);
    dim3 block(256);
    rk4_biosystem_kernel<<<grid, block, 0, stream>>>(y0, t_eval, D_seq, K_m, s_e, mu_max, out);
}